// Round 1
// baseline (739.525 us; speedup 1.0000x reference)
//
#include <hip/hip_runtime.h>
#include <limits.h>

// Problem constants (fixed by the reference: LATTICE=(4096,4096), N_CLUSTERS=262144)
#define N_SITES   (4096 * 4096)      // 16,777,216
#define N_LABELS  262144
#define NWORDS    (N_SITES / 32)     // 524,288 bitmap words
#define WPC       256                // words per chunk
#define NCHUNKS   (NWORDS / WPC)     // 2048

// ---------------- kernel 1: init first_idx + bitmap ----------------
__global__ void k_init(int* __restrict__ first_idx, unsigned* __restrict__ bitmap) {
    int t = blockIdx.x * blockDim.x + threadIdx.x;
    if (t < NWORDS)   bitmap[t] = 0u;
    if (t < N_LABELS) first_idx[t] = INT_MAX;
}

// ---------------- kernel 2: first occurrence per label (segment_min) ----------------
__global__ void k_first(const int4* __restrict__ lab4, int* __restrict__ first_idx, int n4) {
    int t = blockIdx.x * blockDim.x + threadIdx.x;
    if (t >= n4) return;
    int4 L = lab4[t];
    int b  = t * 4;
    atomicMin(&first_idx[L.x], b);
    atomicMin(&first_idx[L.y], b + 1);
    atomicMin(&first_idx[L.z], b + 2);
    atomicMin(&first_idx[L.w], b + 3);
}

// ---------------- kernel 3: scatter seed bits into occupancy bitmap ----------------
__global__ void k_scatter(const int* __restrict__ first_idx, unsigned* __restrict__ bitmap) {
    int l = blockIdx.x * blockDim.x + threadIdx.x;
    if (l >= N_LABELS) return;
    int fi = first_idx[l];
    if (fi != INT_MAX) atomicOr(&bitmap[fi >> 5], 1u << (fi & 31));
}

// ---------------- kernel 4: per-chunk popcount sums ----------------
__global__ void k_chunk_sums(const unsigned* __restrict__ bitmap, int* __restrict__ chunkSums) {
    __shared__ int waveSums[4];
    int w  = blockIdx.x * WPC + threadIdx.x;
    int pc = __popc(bitmap[w]);
    #pragma unroll
    for (int off = 32; off; off >>= 1) pc += __shfl_down(pc, off);
    if ((threadIdx.x & 63) == 0) waveSums[threadIdx.x >> 6] = pc;
    __syncthreads();
    if (threadIdx.x == 0)
        chunkSums[blockIdx.x] = waveSums[0] + waveSums[1] + waveSums[2] + waveSums[3];
}

// ---------------- kernel 5: single-block exclusive scan of chunk sums ----------------
__global__ void k_scan(int* __restrict__ data, int n) {  // n multiple of 256
    __shared__ int lds[256];
    int tid = threadIdx.x;
    int carry = 0;
    for (int base = 0; base < n; base += 256) {
        int v = data[base + tid];
        lds[tid] = v;
        __syncthreads();
        for (int off = 1; off < 256; off <<= 1) {
            int add = (tid >= off) ? lds[tid - off] : 0;
            __syncthreads();
            lds[tid] += add;
            __syncthreads();
        }
        int incl  = lds[tid];
        int total = lds[255];
        __syncthreads();                  // protect lds before next tile overwrite
        data[base + tid] = incl - v + carry;   // exclusive prefix
        carry += total;
    }
}

// ---------------- kernel 6: per-word global exclusive prefix ----------------
__global__ void k_word_prefix(const unsigned* __restrict__ bitmap,
                              const int* __restrict__ chunkPref,
                              int* __restrict__ wordPrefix) {
    __shared__ int lds[256];
    int tid = threadIdx.x;
    int w   = blockIdx.x * WPC + tid;
    int pc  = __popc(bitmap[w]);
    lds[tid] = pc;
    __syncthreads();
    for (int off = 1; off < 256; off <<= 1) {
        int add = (tid >= off) ? lds[tid - off] : 0;
        __syncthreads();
        lds[tid] += add;
        __syncthreads();
    }
    wordPrefix[w] = chunkPref[blockIdx.x] + lds[tid] - pc;  // exclusive
}

// ---------------- kernel 7: rank -> coin -> flip decision per label ----------------
__global__ void k_rank_flip(const int* __restrict__ first_idx,
                            const unsigned* __restrict__ bitmap,
                            const int* __restrict__ wordPrefix,
                            const float* __restrict__ coins,
                            unsigned char* __restrict__ flip) {
    int l = blockIdx.x * blockDim.x + threadIdx.x;
    if (l >= N_LABELS) return;
    int fi = first_idx[l];
    if (fi == INT_MAX) return;           // label absent; flip[l] never read
    int w = fi >> 5;
    unsigned mask = (1u << (fi & 31)) - 1u;
    int rank = wordPrefix[w] + __popc(bitmap[w] & mask);
    flip[l] = (coins[rank] >= 0.5f) ? 1 : 0;
}

// ---------------- kernel 8: apply flips ----------------
__global__ void k_out(const int4* __restrict__ lab4, const float4* __restrict__ sp4,
                      const unsigned char* __restrict__ flip,
                      float4* __restrict__ out4, int n4) {
    int t = blockIdx.x * blockDim.x + threadIdx.x;
    if (t >= n4) return;
    int4   L = lab4[t];
    float4 s = sp4[t];
    float4 o;
    o.x = flip[L.x] ? -s.x : s.x;
    o.y = flip[L.y] ? -s.y : s.y;
    o.z = flip[L.z] ? -s.z : s.z;
    o.w = flip[L.w] ? -s.w : s.w;
    out4[t] = o;
}

extern "C" void kernel_launch(void* const* d_in, const int* in_sizes, int n_in,
                              void* d_out, int out_size, void* d_ws, size_t ws_size,
                              hipStream_t stream) {
    const float* spins  = (const float*)d_in[0];
    const int*   labels = (const int*)d_in[1];
    const float* coins  = (const float*)d_in[2];
    float*       out    = (float*)d_out;

    // workspace layout (total ~5.3 MB)
    char* ws = (char*)d_ws;
    int*           first_idx  = (int*)ws;                              // 1 MB
    unsigned*      bitmap     = (unsigned*)(ws + (1u << 20));          // 2 MB
    int*           wordPrefix = (int*)(ws + 3u * (1u << 20));          // 2 MB
    int*           chunkSums  = (int*)(ws + 5u * (1u << 20));          // 8 KB
    unsigned char* flip       = (unsigned char*)(ws + 5u*(1u<<20) + (1u<<14)); // 256 KB

    const int n  = N_SITES;
    const int n4 = n / 4;

    k_init<<<(NWORDS + 255) / 256, 256, 0, stream>>>(first_idx, bitmap);
    k_first<<<n4 / 256, 256, 0, stream>>>((const int4*)labels, first_idx, n4);
    k_scatter<<<N_LABELS / 256, 256, 0, stream>>>(first_idx, bitmap);
    k_chunk_sums<<<NCHUNKS, WPC, 0, stream>>>(bitmap, chunkSums);
    k_scan<<<1, 256, 0, stream>>>(chunkSums, NCHUNKS);
    k_word_prefix<<<NCHUNKS, WPC, 0, stream>>>(bitmap, chunkSums, wordPrefix);
    k_rank_flip<<<N_LABELS / 256, 256, 0, stream>>>(first_idx, bitmap, wordPrefix, coins, flip);
    k_out<<<n4 / 256, 256, 0, stream>>>((const int4*)labels, (const float4*)spins, flip,
                                        (float4*)out, n4);
}

// Round 2
// 241.206 us; speedup vs baseline: 3.0660x; 3.0660x over previous
//
#include <hip/hip_runtime.h>
#include <limits.h>

// Problem constants (fixed by the reference: LATTICE=(4096,4096), N_CLUSTERS=262144)
#define N_SITES   (4096 * 4096)      // 16,777,216
#define N_LABELS  262144
#define NWORDS    (N_SITES / 32)     // 524,288 bitmap words
#define WPC       256                // words per chunk
#define NCHUNKS   (NWORDS / WPC)     // 2048

// k_first geometry: persistent blocks sweep the array in contiguous segments,
// low indices first, so the early-out filter sees a populated first_idx table
// for all but the first segment.
#define FIRST_BLOCKS 1024
#define FIRST_TPB    256

// ---------------- kernel 1: init first_idx + bitmap ----------------
__global__ void k_init(int* __restrict__ first_idx, unsigned* __restrict__ bitmap) {
    int t = blockIdx.x * blockDim.x + threadIdx.x;
    if (t < NWORDS)   bitmap[t] = 0u;
    if (t < N_LABELS) first_idx[t] = INT_MAX;
}

// ---------------- kernel 2: first occurrence per label (segment_min) ----------------
// Early-out before atomic: first_idx[l] is monotone decreasing from INT_MAX and
// every stored value was legitimately written, so "skip if current <= my index"
// is correct even under stale L1/L2 reads (staleness only causes a redundant,
// harmless atomic). Segmented sweep makes the filter effective: after segment 0
// (~1M sites over 256K labels) the table is ~98% populated, so segments 1..15
// are almost pure reads (labels from HBM, first_idx probes L2-resident).
__global__ void k_first(const int4* __restrict__ lab4, int* __restrict__ first_idx, int n4) {
    const int seg_elems = FIRST_BLOCKS * FIRST_TPB;          // int4 per segment
    int base = blockIdx.x * blockDim.x + threadIdx.x;
    for (int t = base; t < n4; t += seg_elems) {
        int4 L = lab4[t];
        int b  = t * 4;
        if (b     < first_idx[L.x]) atomicMin(&first_idx[L.x], b);
        if (b + 1 < first_idx[L.y]) atomicMin(&first_idx[L.y], b + 1);
        if (b + 2 < first_idx[L.z]) atomicMin(&first_idx[L.z], b + 2);
        if (b + 3 < first_idx[L.w]) atomicMin(&first_idx[L.w], b + 3);
    }
}

// ---------------- kernel 3: scatter seed bits into occupancy bitmap ----------------
__global__ void k_scatter(const int* __restrict__ first_idx, unsigned* __restrict__ bitmap) {
    int l = blockIdx.x * blockDim.x + threadIdx.x;
    if (l >= N_LABELS) return;
    int fi = first_idx[l];
    if (fi != INT_MAX) atomicOr(&bitmap[fi >> 5], 1u << (fi & 31));
}

// ---------------- kernel 4: per-chunk popcount sums ----------------
__global__ void k_chunk_sums(const unsigned* __restrict__ bitmap, int* __restrict__ chunkSums) {
    __shared__ int waveSums[4];
    int w  = blockIdx.x * WPC + threadIdx.x;
    int pc = __popc(bitmap[w]);
    #pragma unroll
    for (int off = 32; off; off >>= 1) pc += __shfl_down(pc, off);
    if ((threadIdx.x & 63) == 0) waveSums[threadIdx.x >> 6] = pc;
    __syncthreads();
    if (threadIdx.x == 0)
        chunkSums[blockIdx.x] = waveSums[0] + waveSums[1] + waveSums[2] + waveSums[3];
}

// ---------------- kernel 5: single-block exclusive scan of chunk sums ----------------
__global__ void k_scan(int* __restrict__ data, int n) {  // n multiple of 256
    __shared__ int lds[256];
    int tid = threadIdx.x;
    int carry = 0;
    for (int base = 0; base < n; base += 256) {
        int v = data[base + tid];
        lds[tid] = v;
        __syncthreads();
        for (int off = 1; off < 256; off <<= 1) {
            int add = (tid >= off) ? lds[tid - off] : 0;
            __syncthreads();
            lds[tid] += add;
            __syncthreads();
        }
        int incl  = lds[tid];
        int total = lds[255];
        __syncthreads();                  // protect lds before next tile overwrite
        data[base + tid] = incl - v + carry;   // exclusive prefix
        carry += total;
    }
}

// ---------------- kernel 6: per-word global exclusive prefix ----------------
__global__ void k_word_prefix(const unsigned* __restrict__ bitmap,
                              const int* __restrict__ chunkPref,
                              int* __restrict__ wordPrefix) {
    __shared__ int lds[256];
    int tid = threadIdx.x;
    int w   = blockIdx.x * WPC + tid;
    int pc  = __popc(bitmap[w]);
    lds[tid] = pc;
    __syncthreads();
    for (int off = 1; off < 256; off <<= 1) {
        int add = (tid >= off) ? lds[tid - off] : 0;
        __syncthreads();
        lds[tid] += add;
        __syncthreads();
    }
    wordPrefix[w] = chunkPref[blockIdx.x] + lds[tid] - pc;  // exclusive
}

// ---------------- kernel 7: rank -> coin -> flip decision per label ----------------
__global__ void k_rank_flip(const int* __restrict__ first_idx,
                            const unsigned* __restrict__ bitmap,
                            const int* __restrict__ wordPrefix,
                            const float* __restrict__ coins,
                            unsigned char* __restrict__ flip) {
    int l = blockIdx.x * blockDim.x + threadIdx.x;
    if (l >= N_LABELS) return;
    int fi = first_idx[l];
    if (fi == INT_MAX) return;           // label absent; flip[l] never read
    int w = fi >> 5;
    unsigned mask = (1u << (fi & 31)) - 1u;
    int rank = wordPrefix[w] + __popc(bitmap[w] & mask);
    flip[l] = (coins[rank] >= 0.5f) ? 1 : 0;
}

// ---------------- kernel 8: apply flips ----------------
__global__ void k_out(const int4* __restrict__ lab4, const float4* __restrict__ sp4,
                      const unsigned char* __restrict__ flip,
                      float4* __restrict__ out4, int n4) {
    int t = blockIdx.x * blockDim.x + threadIdx.x;
    if (t >= n4) return;
    int4   L = lab4[t];
    float4 s = sp4[t];
    float4 o;
    o.x = flip[L.x] ? -s.x : s.x;
    o.y = flip[L.y] ? -s.y : s.y;
    o.z = flip[L.z] ? -s.z : s.z;
    o.w = flip[L.w] ? -s.w : s.w;
    out4[t] = o;
}

extern "C" void kernel_launch(void* const* d_in, const int* in_sizes, int n_in,
                              void* d_out, int out_size, void* d_ws, size_t ws_size,
                              hipStream_t stream) {
    const float* spins  = (const float*)d_in[0];
    const int*   labels = (const int*)d_in[1];
    const float* coins  = (const float*)d_in[2];
    float*       out    = (float*)d_out;

    // workspace layout (total ~5.3 MB)
    char* ws = (char*)d_ws;
    int*           first_idx  = (int*)ws;                              // 1 MB
    unsigned*      bitmap     = (unsigned*)(ws + (1u << 20));          // 2 MB
    int*           wordPrefix = (int*)(ws + 3u * (1u << 20));          // 2 MB
    int*           chunkSums  = (int*)(ws + 5u * (1u << 20));          // 8 KB
    unsigned char* flip       = (unsigned char*)(ws + 5u*(1u<<20) + (1u<<14)); // 256 KB

    const int n  = N_SITES;
    const int n4 = n / 4;

    k_init<<<(NWORDS + 255) / 256, 256, 0, stream>>>(first_idx, bitmap);
    k_first<<<FIRST_BLOCKS, FIRST_TPB, 0, stream>>>((const int4*)labels, first_idx, n4);
    k_scatter<<<N_LABELS / 256, 256, 0, stream>>>(first_idx, bitmap);
    k_chunk_sums<<<NCHUNKS, WPC, 0, stream>>>(bitmap, chunkSums);
    k_scan<<<1, 256, 0, stream>>>(chunkSums, NCHUNKS);
    k_word_prefix<<<NCHUNKS, WPC, 0, stream>>>(bitmap, chunkSums, wordPrefix);
    k_rank_flip<<<N_LABELS / 256, 256, 0, stream>>>(first_idx, bitmap, wordPrefix, coins, flip);
    k_out<<<n4 / 256, 256, 0, stream>>>((const int4*)labels, (const float4*)spins, flip,
                                        (float4*)out, n4);
}